// Round 5
// baseline (176.124 us; speedup 1.0000x reference)
//
#include <hip/hip_runtime.h>
#include <hip/hip_bf16.h>
#include <stdint.h>

// Fused causal attention head, MI355X (gfx950). Round 5.
// R4 lesson: direct global MFMA-fragment loads gather 16 rows/instr ->
// ~16 address segments each -> TA-pipe saturation at ~55-70us regardless of
// occupancy. Fix: coalesced global->LDS staging + ds_read_b128 frags.
// proj: 512 blocks (64 rows x 96-col half), x+W staged to LDS (2 K-phases,
//       <=64KB), pure LDS/MFMA inner loop. 2 blocks/CU.
// attn: 512 blocks x 128thr (2 waves x 16 q), K/V LDS double-buffered,
//       S^T + no-max softmax + b64 P roundtrip (validated R4). Co-residency
//       pairing m = {127-2j | 2(j-64)} keeps per-CU work ~constant.

#define EMBED 384
#define HEAD  64
#define NB    4
#define NT    4096
#define NROWS (NB * NT) // 16384

// 0.125 (1/sqrt(64)) * log2(e) folded into Q at projection time.
#define SCALE_Q 0.18033688011112042f

typedef short bf16x8 __attribute__((ext_vector_type(8))); // 8 bf16 = 4 VGPRs
typedef float f32x4  __attribute__((ext_vector_type(4)));

__device__ __forceinline__ unsigned short bfround(float f) {
    union { float f; unsigned u; } v; v.f = f;
    return (unsigned short)((v.u + 0x8000u) >> 16);
}
__device__ __forceinline__ unsigned packbf(float lo, float hi) {
    union { float f; unsigned u; } a, b; a.f = lo; b.f = hi;
    return ((a.u + 0x8000u) >> 16) | ((b.u + 0x8000u) & 0xFFFF0000u);
}

// ---------------------------------------------------------------------------
// wprep: Wt[n][k] = Wsel[k][n&63] (bf16, [192][384] contiguous rows).
// Coalesced reads (n fastest), scattered 2B stores (fire-and-forget).
// ---------------------------------------------------------------------------
__global__ __launch_bounds__(256)
void wprep_kernel(const float* __restrict__ Wq,
                  const float* __restrict__ Wk,
                  const float* __restrict__ Wv,
                  unsigned short* __restrict__ Wt)
{
    int idx = blockIdx.x * 256 + threadIdx.x; // 0 .. 192*384-1
    int k = idx / 192;
    int n = idx - k * 192;
    int sel = n >> 6, nc = n & 63;
    const float* wp = (sel == 0) ? Wq : ((sel == 1) ? Wk : Wv);
    Wt[n * EMBED + k] = bfround(wp[(size_t)k * HEAD + nc]);
}

// ---------------------------------------------------------------------------
// proj: 512 blocks = 256 row-groups x 2 col-halves. Per block: 64 rows x
// 96 cols. Two K-phases (192 each) staged to LDS coalescedly; inner loop is
// LDS-only. Pitch 200 shorts -> 2-way bank aliasing (free).
// colhalf0 = Q(0:64)+K(0:32); colhalf1 = K(32:64)+V(0:64).
// ---------------------------------------------------------------------------
__global__ __launch_bounds__(256)
void proj_kernel(const float* __restrict__ x,
                 const unsigned short* __restrict__ Wt,
                 unsigned short* __restrict__ Qo,
                 unsigned short* __restrict__ Ko,
                 unsigned short* __restrict__ Vto)
{
    __shared__ __attribute__((aligned(16))) unsigned short ws[96][200]; // 38400 B
    __shared__ __attribute__((aligned(16))) unsigned short xs[64][200]; // 25600 B
    // vbuf aliases xs (only used after all compute + barrier)
    unsigned short (*vbuf)[72] = (unsigned short (*)[72])&xs[0][0]; // 9216 B

    const int t    = threadIdx.x;
    const int w    = t >> 6;
    const int lane = t & 63;
    const int quad = lane >> 4;
    const int l16  = lane & 15;
    const int half = blockIdx.x & 1;
    const int r0   = (blockIdx.x >> 1) * 64;
    const int colbase = half * 96;

    f32x4 acc[6];
#pragma unroll
    for (int i = 0; i < 6; ++i) acc[i] = (f32x4){0.f, 0.f, 0.f, 0.f};

#pragma unroll
    for (int ph = 0; ph < 2; ++ph) {
        if (ph) __syncthreads(); // phase-0 compute done before restage
        const int k0 = ph * 192;
        // stage W half: 96 rows x 192 k (2304 uint4, 9/thread, coalesced)
#pragma unroll
        for (int i = 0; i < 9; ++i) {
            int idx = t + i * 256;
            int row = idx / 24, c = idx - row * 24; // 24 uint4 per row-slice
            *(uint4*)&ws[row][c * 8] =
                *(const uint4*)(Wt + (size_t)(colbase + row) * EMBED + k0 + c * 8);
        }
        // stage x: 64 rows x 192 k fp32->bf16 (3072 float4, 12/thread)
#pragma unroll
        for (int i = 0; i < 12; ++i) {
            int idx = t + i * 256;
            int row = idx / 48, c4 = idx - row * 48; // 48 float4 per row-slice
            const float4 v = *(const float4*)(x + (size_t)(r0 + row) * EMBED + k0 + c4 * 4);
            uint2 pw; pw.x = packbf(v.x, v.y); pw.y = packbf(v.z, v.w);
            *(uint2*)&xs[row][c4 * 4] = pw;
        }
        __syncthreads();
        // 6 k-steps x 6 n-tiles, all LDS
#pragma unroll
        for (int step = 0; step < 6; ++step) {
            bf16x8 a = *(const bf16x8*)&xs[w * 16 + l16][step * 32 + quad * 8];
#pragma unroll
            for (int ng = 0; ng < 6; ++ng) {
                bf16x8 b = *(const bf16x8*)&ws[ng * 16 + l16][step * 32 + quad * 8];
                acc[ng] = __builtin_amdgcn_mfma_f32_16x16x32_bf16(a, b, acc[ng], 0, 0, 0);
            }
        }
    }
    __syncthreads(); // all compute done; xs region becomes vbuf

    // epilogue: C/D layout col=l16, row=quad*4+reg
#pragma unroll
    for (int ng = 0; ng < 6; ++ng) {
        int cg = colbase + ng * 16 + l16;
#pragma unroll
        for (int r = 0; r < 4; ++r) {
            int row = r0 + w * 16 + quad * 4 + r;
            float vv = acc[ng][r];
            if (cg < 64) {
                Qo[(size_t)row * HEAD + cg] = bfround(vv * SCALE_Q);
            } else if (cg < 128) {
                Ko[(size_t)row * HEAD + (cg - 64)] = bfround(vv);
            } else {
                vbuf[cg - 128][w * 16 + quad * 4 + r] = bfround(vv);
            }
        }
    }
    __syncthreads();
    if (half == 1) { // V lives entirely in colhalf1: coalesced Vt stores
        const int batch = r0 >> 12;
        const int s0 = r0 & (NT - 1);
#pragma unroll
        for (int i = 0; i < 2; ++i) {
            int idx = t + i * 256;
            int d = idx >> 3, c = idx & 7;
            *(uint4*)(Vto + ((size_t)(batch * HEAD + d)) * NT + s0 + c * 8) =
                *(const uint4*)&vbuf[d][c * 8];
        }
    }
}

// ---------------------------------------------------------------------------
// attn: 512 blocks x 128 thr. batch = blk&3; j = blk>>2; m (qt32 index) =
// j<64 ? 127-2j : 2(j-64)  -> co-resident block pairs sum to ~65 k-steps.
// Wave w owns q-rows [m*32+w*16, +16). K/V tiles (64 keys) double-buffered
// in LDS; frags via ds_read_b128 (pitch 72 -> 2-way banks, free).
// ---------------------------------------------------------------------------
__global__ __launch_bounds__(128)
void attn_kernel(const unsigned short* __restrict__ Qi,
                 const unsigned short* __restrict__ Ki,
                 const unsigned short* __restrict__ Vti,
                 float* __restrict__ out)
{
    __shared__ __attribute__((aligned(16))) unsigned short Kb[2][64][72];
    __shared__ __attribute__((aligned(16))) unsigned short Vb[2][64][72];
    __shared__ __attribute__((aligned(16))) unsigned short Ps[2][16][72];

    const int t     = threadIdx.x;
    const int w     = t >> 6;
    const int lane  = t & 63;
    const int quad  = lane >> 4;
    const int l16   = lane & 15;
    const int batch = blockIdx.x & 3;
    const int j     = blockIdx.x >> 2;
    const int m     = (j < 64) ? (127 - 2 * j) : (2 * (j - 64));
    const int q0    = m * 32 + w * 16;
    const int dt    = m >> 1; // last k-tile index

    const unsigned short* Kbg = Ki  + (size_t)batch * NT * HEAD;
    const unsigned short* Vbg = Vti + (size_t)batch * HEAD * NT;

    // Q B-frags (one-time 16-row gather; Q carries 0.125*log2e)
    bf16x8 bq0, bq1;
    {
        const unsigned short* qp = Qi + (size_t)(batch * NT + q0 + l16) * HEAD + quad * 8;
        bq0 = *(const bf16x8*)(qp);
        bq1 = *(const bf16x8*)(qp + 32);
    }

    f32x4 o[4];
#pragma unroll
    for (int i = 0; i < 4; ++i) o[i] = (f32x4){0.f, 0.f, 0.f, 0.f};
    float rs = 0.f;

    uint4 kreg[4], vreg[4];
    // prologue: tile 0 -> regs -> LDS buf 0 (coalesced 8-uint4-per-row)
#pragma unroll
    for (int i = 0; i < 4; ++i) {
        int idx = t + i * 128;
        int row = idx >> 3, c = idx & 7;
        kreg[i] = *(const uint4*)(Kbg + (size_t)row * HEAD + c * 8);
        vreg[i] = *(const uint4*)(Vbg + (size_t)row * NT + c * 8);
    }
#pragma unroll
    for (int i = 0; i < 4; ++i) {
        int idx = t + i * 128;
        int row = idx >> 3, c = idx & 7;
        *(uint4*)&Kb[0][row][c * 8] = kreg[i];
        *(uint4*)&Vb[0][row][c * 8] = vreg[i];
    }

    for (int kt = 0; kt <= dt; ++kt) {
        if (kt < dt) { // prefetch next tile into regs (overlaps compute)
#pragma unroll
            for (int i = 0; i < 4; ++i) {
                int idx = t + i * 128;
                int row = idx >> 3, c = idx & 7;
                kreg[i] = *(const uint4*)(Kbg + (size_t)((kt + 1) * 64 + row) * HEAD + c * 8);
                vreg[i] = *(const uint4*)(Vbg + (size_t)row * NT + (kt + 1) * 64 + c * 8);
            }
        }
        __syncthreads(); // buf[kt&1] fully written
        const int buf = kt & 1;

        bf16x8 ak0[4], ak1[4], av0[4], av1[4];
#pragma unroll
        for (int ts = 0; ts < 4; ++ts) {
            ak0[ts] = *(const bf16x8*)&Kb[buf][ts * 16 + l16][quad * 8];
            ak1[ts] = *(const bf16x8*)&Kb[buf][ts * 16 + l16][32 + quad * 8];
        }
#pragma unroll
        for (int nd = 0; nd < 4; ++nd) {
            av0[nd] = *(const bf16x8*)&Vb[buf][nd * 16 + l16][quad * 8];
            av1[nd] = *(const bf16x8*)&Vb[buf][nd * 16 + l16][32 + quad * 8];
        }

        const bool diag = (kt == dt);
#pragma unroll
        for (int ts = 0; ts < 4; ++ts) {
            f32x4 z = (f32x4){0.f, 0.f, 0.f, 0.f};
            z = __builtin_amdgcn_mfma_f32_16x16x32_bf16(ak0[ts], bq0, z, 0, 0, 0);
            z = __builtin_amdgcn_mfma_f32_16x16x32_bf16(ak1[ts], bq1, z, 0, 0, 0);
            // z[r] = S^T[s = kt*64+ts*16+quad*4+r][q = q0+l16], exp2 domain
            float p[4];
#pragma unroll
            for (int r = 0; r < 4; ++r) {
                float pv = __builtin_amdgcn_exp2f(z[r]);
                if (diag) {
                    int s = kt * 64 + ts * 16 + quad * 4 + r;
                    pv = (s > q0 + l16) ? 0.f : pv;
                }
                p[r] = pv;
            }
            rs += (p[0] + p[1]) + (p[2] + p[3]);
            uint2 pw; pw.x = packbf(p[0], p[1]); pw.y = packbf(p[2], p[3]);
            *(uint2*)&Ps[w][l16][ts * 16 + quad * 4] = pw;
        }
        // P C-layout -> A-frags (same-wave in-order DS; validated R4)
        bf16x8 ap0 = *(const bf16x8*)&Ps[w][l16][quad * 8];
        bf16x8 ap1 = *(const bf16x8*)&Ps[w][l16][32 + quad * 8];
#pragma unroll
        for (int nd = 0; nd < 4; ++nd) {
            o[nd] = __builtin_amdgcn_mfma_f32_16x16x32_bf16(ap0, av0[nd], o[nd], 0, 0, 0);
            o[nd] = __builtin_amdgcn_mfma_f32_16x16x32_bf16(ap1, av1[nd], o[nd], 0, 0, 0);
        }

        if (kt < dt) {
            __syncthreads(); // all waves done reading buf[(kt+1)&1]
            const int nbuf = (kt + 1) & 1;
#pragma unroll
            for (int i = 0; i < 4; ++i) {
                int idx = t + i * 128;
                int row = idx >> 3, c = idx & 7;
                *(uint4*)&Kb[nbuf][row][c * 8] = kreg[i];
                *(uint4*)&Vb[nbuf][row][c * 8] = vreg[i];
            }
        }
    }

    // rs: butterfly across quads -> every lane holds sum for q = q0 + l16
    rs += __shfl_xor(rs, 16, 64);
    rs += __shfl_xor(rs, 32, 64);
#pragma unroll
    for (int r = 0; r < 4; ++r) {
        float iv = 1.0f / __shfl(rs, quad * 4 + r, 64);
        size_t off = (size_t)(batch * NT + q0 + quad * 4 + r) * HEAD;
#pragma unroll
        for (int nd = 0; nd < 4; ++nd)
            out[off + nd * 16 + l16] = o[nd][r] * iv;
    }
}

extern "C" void kernel_launch(void* const* d_in, const int* in_sizes, int n_in,
                              void* d_out, int out_size, void* d_ws, size_t ws_size,
                              hipStream_t stream)
{
    const float* x  = (const float*)d_in[0];
    const float* Wq = (const float*)d_in[1];
    const float* Wk = (const float*)d_in[2];
    const float* Wv = (const float*)d_in[3];
    float* out = (float*)d_out;

    // ws: Q | K | V^T (bf16, 2MB each) | W^T (bf16, 144KB)
    unsigned short* Qw  = (unsigned short*)d_ws;
    unsigned short* Kw  = Qw + (size_t)NROWS * HEAD;
    unsigned short* Vtw = Kw + (size_t)NROWS * HEAD;
    unsigned short* Wtw = Vtw + (size_t)NROWS * HEAD;

    wprep_kernel<<<(192 * EMBED) / 256, 256, 0, stream>>>(Wq, Wk, Wv, Wtw);
    proj_kernel<<<512, 256, 0, stream>>>(x, Wtw, Qw, Kw, Vtw);
    attn_kernel<<<512, 128, 0, stream>>>(Qw, Kw, Vtw, out);
}

// Round 6
// 127.568 us; speedup vs baseline: 1.3806x; 1.3806x over previous
//
#include <hip/hip_runtime.h>
#include <hip/hip_bf16.h>
#include <stdint.h>

// Fused causal attention head, MI355X (gfx950). Round 6.
// attn redesign: 64-q-row block (4 waves), split-K=2 across blocks (no-max
// softmax => additive partials), K/V staged to LDS with XOR-swizzled chunks
// (conflict-free b128 frags), 32-iter max critical path, LPT pairing.
// opart/lpart partials in ws; combine kernel normalizes.
// proj/wprep kept identical to R5 for clean attribution.

#define EMBED 384
#define HEAD  64
#define NB    4
#define NT    4096
#define NROWS (NB * NT) // 16384

#define SCALE_Q 0.18033688011112042f // 0.125 * log2(e), folded into Q

typedef short bf16x8 __attribute__((ext_vector_type(8)));
typedef float f32x4  __attribute__((ext_vector_type(4)));

__device__ __forceinline__ unsigned short bfround(float f) {
    union { float f; unsigned u; } v; v.f = f;
    return (unsigned short)((v.u + 0x8000u) >> 16);
}
__device__ __forceinline__ unsigned packbf(float lo, float hi) {
    union { float f; unsigned u; } a, b; a.f = lo; b.f = hi;
    return ((a.u + 0x8000u) >> 16) | ((b.u + 0x8000u) & 0xFFFF0000u);
}

// ---------------------------------------------------------------------------
__global__ __launch_bounds__(256)
void wprep_kernel(const float* __restrict__ Wq,
                  const float* __restrict__ Wk,
                  const float* __restrict__ Wv,
                  unsigned short* __restrict__ Wt)
{
    int idx = blockIdx.x * 256 + threadIdx.x;
    int k = idx / 192;
    int n = idx - k * 192;
    int sel = n >> 6, nc = n & 63;
    const float* wp = (sel == 0) ? Wq : ((sel == 1) ? Wk : Wv);
    Wt[n * EMBED + k] = bfround(wp[(size_t)k * HEAD + nc]);
}

// ---------------------------------------------------------------------------
// proj: identical to R5 (kept for attribution).
// ---------------------------------------------------------------------------
__global__ __launch_bounds__(256)
void proj_kernel(const float* __restrict__ x,
                 const unsigned short* __restrict__ Wt,
                 unsigned short* __restrict__ Qo,
                 unsigned short* __restrict__ Ko,
                 unsigned short* __restrict__ Vto)
{
    __shared__ __attribute__((aligned(16))) unsigned short ws[96][200];
    __shared__ __attribute__((aligned(16))) unsigned short xs[64][200];
    unsigned short (*vbuf)[72] = (unsigned short (*)[72])&xs[0][0];

    const int t    = threadIdx.x;
    const int w    = t >> 6;
    const int lane = t & 63;
    const int quad = lane >> 4;
    const int l16  = lane & 15;
    const int half = blockIdx.x & 1;
    const int r0   = (blockIdx.x >> 1) * 64;
    const int colbase = half * 96;

    f32x4 acc[6];
#pragma unroll
    for (int i = 0; i < 6; ++i) acc[i] = (f32x4){0.f, 0.f, 0.f, 0.f};

#pragma unroll
    for (int ph = 0; ph < 2; ++ph) {
        if (ph) __syncthreads();
        const int k0 = ph * 192;
#pragma unroll
        for (int i = 0; i < 9; ++i) {
            int idx = t + i * 256;
            int row = idx / 24, c = idx - row * 24;
            *(uint4*)&ws[row][c * 8] =
                *(const uint4*)(Wt + (size_t)(colbase + row) * EMBED + k0 + c * 8);
        }
#pragma unroll
        for (int i = 0; i < 12; ++i) {
            int idx = t + i * 256;
            int row = idx / 48, c4 = idx - row * 48;
            const float4 v = *(const float4*)(x + (size_t)(r0 + row) * EMBED + k0 + c4 * 4);
            uint2 pw; pw.x = packbf(v.x, v.y); pw.y = packbf(v.z, v.w);
            *(uint2*)&xs[row][c4 * 4] = pw;
        }
        __syncthreads();
#pragma unroll
        for (int step = 0; step < 6; ++step) {
            bf16x8 a = *(const bf16x8*)&xs[w * 16 + l16][step * 32 + quad * 8];
#pragma unroll
            for (int ng = 0; ng < 6; ++ng) {
                bf16x8 b = *(const bf16x8*)&ws[ng * 16 + l16][step * 32 + quad * 8];
                acc[ng] = __builtin_amdgcn_mfma_f32_16x16x32_bf16(a, b, acc[ng], 0, 0, 0);
            }
        }
    }
    __syncthreads();

#pragma unroll
    for (int ng = 0; ng < 6; ++ng) {
        int cg = colbase + ng * 16 + l16;
#pragma unroll
        for (int r = 0; r < 4; ++r) {
            int row = r0 + w * 16 + quad * 4 + r;
            float vv = acc[ng][r];
            if (cg < 64) {
                Qo[(size_t)row * HEAD + cg] = bfround(vv * SCALE_Q);
            } else if (cg < 128) {
                Ko[(size_t)row * HEAD + (cg - 64)] = bfround(vv);
            } else {
                vbuf[cg - 128][w * 16 + quad * 4 + r] = bfround(vv);
            }
        }
    }
    __syncthreads();
    if (half == 1) {
        const int batch = r0 >> 12;
        const int s0 = r0 & (NT - 1);
#pragma unroll
        for (int i = 0; i < 2; ++i) {
            int idx = t + i * 256;
            int d = idx >> 3, c = idx & 7;
            *(uint4*)(Vto + ((size_t)(batch * HEAD + d)) * NT + s0 + c * 8) =
                *(const uint4*)&vbuf[d][c * 8];
        }
    }
}

// ---------------------------------------------------------------------------
// attn: 512 blocks x 256 thr. u<256: m=63-(u>>2), split=0; else m=(u-256)>>2,
// split=1; batch=u&3 (XCD-pinned: XCD k always sees batch k&3). Block covers
// q-rows [m*64, m*64+64), wave w owns 16 of them. k-tiles kt = split, +2 ...
// <= m (diag tile kt==m belongs to split m&1 automatically).
// LPT pairing: co-resident pair (u, u+256) works m and 63-m -> ~33 iters/CU.
// K/V tiles in LDS, XOR-swizzled 16B chunks: phys chunk = c ^ (row&7) ->
// both staging writes and frag reads are <=2-way bank aliased (free).
// ---------------------------------------------------------------------------
__global__ __launch_bounds__(256)
void attn_kernel(const unsigned short* __restrict__ Qi,
                 const unsigned short* __restrict__ Ki,
                 const unsigned short* __restrict__ Vti,
                 float* __restrict__ opart,
                 float* __restrict__ lpart)
{
    __shared__ __attribute__((aligned(16))) unsigned short Kt[64][64];
    __shared__ __attribute__((aligned(16))) unsigned short Vs[64][64];
    __shared__ __attribute__((aligned(16))) unsigned short Ps[4][16][72];

    const int t    = threadIdx.x;
    const int w    = t >> 6;
    const int lane = t & 63;
    const int quad = lane >> 4;
    const int l16  = lane & 15;

    const int u = blockIdx.x;
    int m, sp, batch;
    if (u < 256) { m = 63 - (u >> 2); sp = 0; batch = u & 3; }
    else         { int v = u - 256; m = v >> 2; sp = 1; batch = v & 3; }
    const int ntiles = (m >= sp) ? (((m - sp) >> 1) + 1) : 0;
    const int q0 = m * 64 + w * 16; // this wave's q-row base

    const unsigned short* Kbg = Ki  + (size_t)batch * NT * HEAD;
    const unsigned short* Vbg = Vti + (size_t)batch * HEAD * NT;

    // Q B-frags (one-time; Q carries 0.125*log2e)
    bf16x8 bq0, bq1;
    {
        const unsigned short* qp = Qi + (size_t)(batch * NT + q0 + l16) * HEAD + quad * 8;
        bq0 = *(const bf16x8*)(qp);
        bq1 = *(const bf16x8*)(qp + 32);
    }

    f32x4 o[4];
#pragma unroll
    for (int i = 0; i < 4; ++i) o[i] = (f32x4){0.f, 0.f, 0.f, 0.f};
    float rs = 0.f;

    // staging indices (fixed per thread): 2 chunks each of K and V
    const int srow0 = t >> 3, sc = t & 7;           // idx = t
    const int srow1 = (t + 256) >> 3;               // idx = t + 256
    const int scc0 = sc ^ (srow0 & 7);              // swizzled chunk
    const int scc1 = sc ^ (srow1 & 7);

    for (int j = 0; j < ntiles; ++j) {
        const int kt = sp + 2 * j;
        // coalesced global loads into regs (latency overlaps barrier wait)
        uint4 kr0 = *(const uint4*)(Kbg + (size_t)(kt * 64 + srow0) * HEAD + sc * 8);
        uint4 kr1 = *(const uint4*)(Kbg + (size_t)(kt * 64 + srow1) * HEAD + sc * 8);
        uint4 vr0 = *(const uint4*)(Vbg + (size_t)srow0 * NT + kt * 64 + sc * 8);
        uint4 vr1 = *(const uint4*)(Vbg + (size_t)srow1 * NT + kt * 64 + sc * 8);
        __syncthreads(); // previous iteration's LDS reads complete
        *(uint4*)&Kt[srow0][scc0 * 8] = kr0;
        *(uint4*)&Kt[srow1][scc1 * 8] = kr1;
        *(uint4*)&Vs[srow0][scc0 * 8] = vr0;
        *(uint4*)&Vs[srow1][scc1 * 8] = vr1;
        __syncthreads(); // tile visible

        const int sw = l16 & 7; // row-swizzle key for frag reads
        const bool diag = (kt == m);
#pragma unroll
        for (int ts = 0; ts < 4; ++ts) {
            bf16x8 ak0 = *(const bf16x8*)&Kt[ts * 16 + l16][(quad ^ sw) * 8];
            bf16x8 ak1 = *(const bf16x8*)&Kt[ts * 16 + l16][((4 + quad) ^ sw) * 8];
            f32x4 z = (f32x4){0.f, 0.f, 0.f, 0.f};
            z = __builtin_amdgcn_mfma_f32_16x16x32_bf16(ak0, bq0, z, 0, 0, 0);
            z = __builtin_amdgcn_mfma_f32_16x16x32_bf16(ak1, bq1, z, 0, 0, 0);
            // z[r] = S^T[s = kt*64+ts*16+quad*4+r][q = q0+l16], exp2 domain
            float p[4];
#pragma unroll
            for (int r = 0; r < 4; ++r) {
                float pv = __builtin_amdgcn_exp2f(z[r]);
                if (diag) {
                    int sg = kt * 64 + ts * 16 + quad * 4 + r;
                    pv = (sg > q0 + l16) ? 0.f : pv;
                }
                p[r] = pv;
            }
            rs += (p[0] + p[1]) + (p[2] + p[3]);
            uint2 pw; pw.x = packbf(p[0], p[1]); pw.y = packbf(p[2], p[3]);
            *(uint2*)&Ps[w][l16][ts * 16 + quad * 4] = pw;
        }
        // P C-layout -> A-frags (same-wave LDS roundtrip)
        bf16x8 ap0 = *(const bf16x8*)&Ps[w][l16][quad * 8];
        bf16x8 ap1 = *(const bf16x8*)&Ps[w][l16][32 + quad * 8];
#pragma unroll
        for (int nd = 0; nd < 4; ++nd) {
            bf16x8 av0 = *(const bf16x8*)&Vs[nd * 16 + l16][(quad ^ sw) * 8];
            bf16x8 av1 = *(const bf16x8*)&Vs[nd * 16 + l16][((4 + quad) ^ sw) * 8];
            o[nd] = __builtin_amdgcn_mfma_f32_16x16x32_bf16(ap0, av0, o[nd], 0, 0, 0);
            o[nd] = __builtin_amdgcn_mfma_f32_16x16x32_bf16(ap1, av1, o[nd], 0, 0, 0);
        }
    }

    // rs: butterfly across quads -> lane holds sum for q = q0 + l16
    rs += __shfl_xor(rs, 16, 64);
    rs += __shfl_xor(rs, 32, 64);
    if (quad == 0)
        lpart[(size_t)sp * NROWS + batch * NT + q0 + l16] = rs;
    float* ob = opart + (size_t)sp * NROWS * HEAD;
#pragma unroll
    for (int r = 0; r < 4; ++r) {
        size_t off = (size_t)(batch * NT + q0 + quad * 4 + r) * HEAD;
#pragma unroll
        for (int nd = 0; nd < 4; ++nd)
            ob[off + nd * 16 + l16] = o[nd][r];
    }
}

// ---------------------------------------------------------------------------
// combine: out = (o0 + o1) / (l0 + l1), one float4 per thread.
// ---------------------------------------------------------------------------
__global__ __launch_bounds__(256)
void combine_kernel(const float* __restrict__ opart,
                    const float* __restrict__ lpart,
                    float* __restrict__ out)
{
    int gid = blockIdx.x * 256 + threadIdx.x;   // 0 .. NROWS*16-1
    int row = gid >> 4;
    int d4  = (gid & 15) * 4;
    f32x4 a = *(const f32x4*)(opart + (size_t)row * HEAD + d4);
    f32x4 b = *(const f32x4*)(opart + (size_t)NROWS * HEAD + (size_t)row * HEAD + d4);
    float inv = 1.0f / (lpart[row] + lpart[NROWS + row]);
    f32x4 res = (a + b);
    res[0] *= inv; res[1] *= inv; res[2] *= inv; res[3] *= inv;
    *(f32x4*)(out + (size_t)row * HEAD + d4) = res;
}

extern "C" void kernel_launch(void* const* d_in, const int* in_sizes, int n_in,
                              void* d_out, int out_size, void* d_ws, size_t ws_size,
                              hipStream_t stream)
{
    const float* x  = (const float*)d_in[0];
    const float* Wq = (const float*)d_in[1];
    const float* Wk = (const float*)d_in[2];
    const float* Wv = (const float*)d_in[3];
    float* out = (float*)d_out;

    // ws: Q | K | V^T (bf16, 2MB each) | W^T (144KB) | opart (8MB) | lpart (128KB)
    unsigned short* Qw  = (unsigned short*)d_ws;
    unsigned short* Kw  = Qw + (size_t)NROWS * HEAD;
    unsigned short* Vtw = Kw + (size_t)NROWS * HEAD;
    unsigned short* Wtw = Vtw + (size_t)NROWS * HEAD;
    float* opart = (float*)(Wtw + (size_t)192 * EMBED);
    float* lpart = opart + (size_t)2 * NROWS * HEAD;

    wprep_kernel<<<(192 * EMBED) / 256, 256, 0, stream>>>(Wq, Wk, Wv, Wtw);
    proj_kernel<<<512, 256, 0, stream>>>(x, Wtw, Qw, Kw, Vtw);
    attn_kernel<<<512, 256, 0, stream>>>(Qw, Kw, Vtw, opart, lpart);
    combine_kernel<<<NROWS * 16 / 256, 256, 0, stream>>>(opart, lpart, out);
}